// Round 6
// baseline (862.459 us; speedup 1.0000x reference)
//
#include <hip/hip_runtime.h>
#include <math.h>

// Problem dims
#define BDIM 1024
#define RDIM 1152
#define IDIM 8
#define CDIM 10
#define ODIM 16
#define CO   160   // CDIM*ODIM

constexpr int T_BATCH = 4;                      // batches per k_s block
constexpr int RSPLIT = 4;                       // r splits in k_s
constexpr int R_PER_SPLIT = RDIM / RSPLIT;      // 288
constexpr int CHUNK = 32;                       // r chunk staged in LDS

// workspace layout (in floats)
constexpr size_t OFF_BL = 0;                                  // b logits (B,R,C)
constexpr size_t SZ_BL  = (size_t)BDIM * RDIM * CDIM;         // 11,796,480
constexpr size_t OFF_V  = OFF_BL + SZ_BL;                     // v (B,C,O)
constexpr size_t SZ_V   = (size_t)BDIM * CO;                  // 163,840
constexpr size_t OFF_ST = OFF_V + SZ_V;                       // stats (B,C,2): max, 1/sumexp
constexpr size_t SZ_ST  = (size_t)BDIM * CDIM * 2;            // 20,480
constexpr size_t OFF_SP = OFF_ST + SZ_ST;                     // s partials (RSPLIT,B,C,O)

// ---------------------------------------------------------------------------
// k_s: s_part[split][b][c][o] = sum_{r in split} cval(b,r,c) * u_hat(b,r,c,o)
//   MODE 0: cval = 1 (scaled by 1/R at the end)  [iteration 0, softmax(0)=uniform]
//   MODE 1: cval = exp(bl - max) * inv_sumexp    [softmax over R]
// u_hat(b,r,c,o) = sum_i x[b,r,i] * W[r,i,c,o], recomputed on the fly.
// ---------------------------------------------------------------------------
template <int MODE>
__global__ __launch_bounds__(192) void k_s(const float* __restrict__ x,
                                           const float* __restrict__ W,
                                           const float* __restrict__ bl,
                                           const float* __restrict__ stats,
                                           float* __restrict__ s_part) {
    __shared__ float xs[T_BATCH][CHUNK][IDIM];   // 4 KB
    __shared__ float cv[T_BATCH][CHUNK][CDIM];   // 5 KB
    const int t = threadIdx.x;
    const int bt0 = blockIdx.x * T_BATCH;
    const int r0 = blockIdx.y * R_PER_SPLIT;
    const int c = t >> 4;                        // owner's capsule index (t < 160)

    float acc[T_BATCH] = {0.f, 0.f, 0.f, 0.f};

    for (int rc = 0; rc < R_PER_SPLIT; rc += CHUNK) {
        // stage x chunk: 4 batches x 32 r x 8 i = 1024 floats (contiguous per batch)
        for (int e = t; e < T_BATCH * CHUNK * IDIM; e += 192) {
            int bt = e >> 8;          // /256
            int rem = e & 255;        // r*8+i within chunk
            xs[bt][rem >> 3][rem & 7] =
                x[(size_t)(bt0 + bt) * RDIM * IDIM + (size_t)(r0 + rc) * IDIM + rem];
        }
        if (MODE == 1) {
            // stage softmax coefficients: 4 x 32 x 10 = 1280 floats
            for (int e = t; e < T_BATCH * CHUNK * CDIM; e += 192) {
                int bt = e / 320;
                int rem = e - bt * 320;    // rr*10 + c
                int cc = rem % 10;
                float m   = stats[(size_t)(bt0 + bt) * CDIM * 2 + cc * 2 + 0];
                float inv = stats[(size_t)(bt0 + bt) * CDIM * 2 + cc * 2 + 1];
                float bv  = bl[(size_t)(bt0 + bt) * RDIM * CDIM +
                               (size_t)(r0 + rc) * CDIM + rem];
                cv[bt][rem / 10][cc] = __expf(bv - m) * inv;
            }
        }
        __syncthreads();

        if (t < CO) {
            for (int rr = 0; rr < CHUNK; ++rr) {
                const float* wp = W + (size_t)(r0 + rc + rr) * IDIM * CO + t;
                float w0 = wp[0 * CO], w1 = wp[1 * CO], w2 = wp[2 * CO], w3 = wp[3 * CO];
                float w4 = wp[4 * CO], w5 = wp[5 * CO], w6 = wp[6 * CO], w7 = wp[7 * CO];
#pragma unroll
                for (int bt = 0; bt < T_BATCH; ++bt) {
                    const float4 xa = *reinterpret_cast<const float4*>(&xs[bt][rr][0]);
                    const float4 xb = *reinterpret_cast<const float4*>(&xs[bt][rr][4]);
                    float u = xa.x * w0 + xa.y * w1 + xa.z * w2 + xa.w * w3 +
                              xb.x * w4 + xb.y * w5 + xb.z * w6 + xb.w * w7;
                    if (MODE == 1) {
                        acc[bt] += cv[bt][rr][c] * u;
                    } else {
                        acc[bt] += u;
                    }
                }
            }
        }
        __syncthreads();
    }

    if (t < CO) {
#pragma unroll
        for (int bt = 0; bt < T_BATCH; ++bt) {
            float val = acc[bt];
            if (MODE == 0) val *= (1.0f / RDIM);
            s_part[((size_t)blockIdx.y * BDIM + (bt0 + bt)) * CO + t] = val;
        }
    }
}

// ---------------------------------------------------------------------------
// k_squash: s = sum over partials; v = (n/(n+1)) * s / sqrt(n), n = |s|^2 over O
// ---------------------------------------------------------------------------
__global__ __launch_bounds__(256) void k_squash(const float* __restrict__ s_part,
                                                float* __restrict__ dst) {
    int g = blockIdx.x * 256 + threadIdx.x;   // grid covers B*CO = 163840
    int b = g / CO;
    int co = g - b * CO;
    float s = 0.f;
#pragma unroll
    for (int p = 0; p < RSPLIT; ++p)
        s += s_part[((size_t)p * BDIM + b) * CO + co];
    float sq = s * s;
    // 160 % 16 == 0 so o-groups of 16 stay lane-aligned within a wave
    sq += __shfl_xor(sq, 1, 16);
    sq += __shfl_xor(sq, 2, 16);
    sq += __shfl_xor(sq, 4, 16);
    sq += __shfl_xor(sq, 8, 16);
    float n = sq;
    float val = (n / (n + 1.0f)) * s / sqrtf(n);
    dst[g] = val;
}

// ---------------------------------------------------------------------------
// k_b: bl[b,r,c] (+)= sum_o u_hat(b,r,c,o) * v[b,c,o]
// block: 16 r x 64 batches, 640 threads = (bt, c)
// ---------------------------------------------------------------------------
template <int ACC>
__global__ __launch_bounds__(640) void k_b(const float* __restrict__ x,
                                           const float* __restrict__ W,
                                           const float* __restrict__ v,
                                           float* __restrict__ bl) {
    constexpr int RT = 16, BT = 64;
    __shared__ float xs[RT][BT][IDIM + 1];   // pad to 9 -> conflict-free reads (36,864 B)
    __shared__ float wsm[IDIM][CO];          // one r's W slice (5,120 B)
    const int t = threadIdx.x;
    const int r0 = blockIdx.x * RT;
    const int b0 = blockIdx.y * BT;
    const int bt = t / CDIM;                 // 0..63
    const int c = t - bt * CDIM;             // 0..9

    // stage x tile: 16 r x 64 b x 8 i
    for (int e = t; e < RT * BT * IDIM; e += 640) {
        int rr = e >> 9;          // /512
        int rem = e & 511;
        int bb = rem >> 3;
        int i = rem & 7;
        xs[rr][bb][i] = x[(size_t)(b0 + bb) * RDIM * IDIM + (size_t)(r0 + rr) * IDIM + i];
    }

    // v row for this (batch, capsule) in registers
    float vr[ODIM];
    {
        const float* vp = v + (size_t)(b0 + bt) * CO + c * ODIM;
#pragma unroll
        for (int o = 0; o < ODIM; o += 4) {
            float4 q = *reinterpret_cast<const float4*>(vp + o);
            vr[o] = q.x; vr[o + 1] = q.y; vr[o + 2] = q.z; vr[o + 3] = q.w;
        }
    }

    for (int rr = 0; rr < RT; ++rr) {
        __syncthreads();   // protect wsm from previous iteration's readers (and xs on iter 0)
        for (int e = t; e < IDIM * CO; e += 640) {
            wsm[e / CO][e - (e / CO) * CO] = W[(size_t)(r0 + rr) * IDIM * CO + e];
        }
        __syncthreads();

        float u[ODIM];
#pragma unroll
        for (int o = 0; o < ODIM; ++o) u[o] = 0.f;
#pragma unroll
        for (int i = 0; i < IDIM; ++i) {
            float xi = xs[rr][bt][i];
#pragma unroll
            for (int o4 = 0; o4 < ODIM; o4 += 4) {
                float4 w4 = *reinterpret_cast<const float4*>(&wsm[i][c * ODIM + o4]);
                u[o4]     += xi * w4.x;
                u[o4 + 1] += xi * w4.y;
                u[o4 + 2] += xi * w4.z;
                u[o4 + 3] += xi * w4.w;
            }
        }
        float bacc = 0.f;
#pragma unroll
        for (int o = 0; o < ODIM; ++o) bacc += u[o] * vr[o];

        size_t idx = (size_t)(b0 + bt) * RDIM * CDIM + (size_t)(r0 + rr) * CDIM + c;
        if (ACC) {
            bl[idx] = bl[idx] + bacc;
        } else {
            bl[idx] = bacc;
        }
    }
}

// ---------------------------------------------------------------------------
// k_stats: per (b,c): max over r of bl, and 1/sum(exp(bl-max))
// ---------------------------------------------------------------------------
__global__ __launch_bounds__(256) void k_stats(const float* __restrict__ bl,
                                               float* __restrict__ stats) {
    __shared__ float sb[RDIM * CDIM];   // 46,080 B
    __shared__ float red[4];
    const int t = threadIdx.x;
    const int b = blockIdx.x;
    const int wave = t >> 6, lane = t & 63;

    for (int e = t; e < RDIM * CDIM; e += 256)
        sb[e] = bl[(size_t)b * RDIM * CDIM + e];
    __syncthreads();

    for (int c = 0; c < CDIM; ++c) {
        float m = -1e30f;
        for (int r = t; r < RDIM; r += 256)
            m = fmaxf(m, sb[r * CDIM + c]);
        for (int d = 1; d < 64; d <<= 1)
            m = fmaxf(m, __shfl_xor(m, d, 64));
        if (lane == 0) red[wave] = m;
        __syncthreads();
        m = fmaxf(fmaxf(red[0], red[1]), fmaxf(red[2], red[3]));
        __syncthreads();   // all readers done before red reuse

        float se = 0.f;
        for (int r = t; r < RDIM; r += 256)
            se += __expf(sb[r * CDIM + c] - m);
        for (int d = 1; d < 64; d <<= 1)
            se += __shfl_xor(se, d, 64);
        if (lane == 0) red[wave] = se;
        __syncthreads();
        se = red[0] + red[1] + red[2] + red[3];
        if (t == 0) {
            stats[(size_t)b * CDIM * 2 + c * 2 + 0] = m;
            stats[(size_t)b * CDIM * 2 + c * 2 + 1] = 1.0f / se;
        }
        __syncthreads();   // before next c overwrites red
    }
}

// ---------------------------------------------------------------------------
extern "C" void kernel_launch(void* const* d_in, const int* in_sizes, int n_in,
                              void* d_out, int out_size, void* d_ws, size_t ws_size,
                              hipStream_t stream) {
    const float* x = (const float*)d_in[0];
    const float* W = (const float*)d_in[1];
    float* out = (float*)d_out;
    float* ws = (float*)d_ws;

    float* bl = ws + OFF_BL;
    float* v  = ws + OFF_V;
    float* st = ws + OFF_ST;
    float* sp = ws + OFF_SP;

    dim3 gs(BDIM / T_BATCH, RSPLIT);           // 256 x 4 blocks
    dim3 gb(RDIM / 16, BDIM / 64);             // 72 x 16 blocks

    // iteration 0: softmax(0) is uniform -> s0 = mean_r u_hat
    k_s<0><<<gs, 192, 0, stream>>>(x, W, bl, st, sp);
    k_squash<<<(BDIM * CO) / 256, 256, 0, stream>>>(sp, v);
    k_b<0><<<gb, 640, 0, stream>>>(x, W, v, bl);     // b1 = u_hat . v0

    // iteration 1
    k_stats<<<BDIM, 256, 0, stream>>>(bl, st);
    k_s<1><<<gs, 192, 0, stream>>>(x, W, bl, st, sp);
    k_squash<<<(BDIM * CO) / 256, 256, 0, stream>>>(sp, v);
    k_b<1><<<gb, 640, 0, stream>>>(x, W, v, bl);     // b2 = b1 + u_hat . v1

    // iteration 2 (final; no b update)
    k_stats<<<BDIM, 256, 0, stream>>>(bl, st);
    k_s<1><<<gs, 192, 0, stream>>>(x, W, bl, st, sp);
    k_squash<<<(BDIM * CO) / 256, 256, 0, stream>>>(sp, out);
}

// Round 7
// 473.240 us; speedup vs baseline: 1.8225x; 1.8225x over previous
//
#include <hip/hip_runtime.h>
#include <math.h>

// Problem dims
#define BDIM 1024
#define RDIM 1152
#define IDIM 8
#define CDIM 10
#define ODIM 16
#define CO   160   // CDIM*ODIM

typedef _Float16 half_t;
typedef half_t f16x4 __attribute__((ext_vector_type(4)));
typedef half_t f16x8 __attribute__((ext_vector_type(8)));
typedef float  f32x4 __attribute__((ext_vector_type(4)));

constexpr int RSPLIT = 16;                      // r splits in k_s
constexpr int R_PER_SPLIT = RDIM / RSPLIT;      // 72
constexpr int CH_R = 8;                         // r chunk per stage (2 MFMA k-steps)

// workspace layout (in float units)
constexpr size_t OFF_BL = 0;                                  // b logits (B,R,C) f32
constexpr size_t SZ_BL  = (size_t)BDIM * RDIM * CDIM;         // 11,796,480
constexpr size_t OFF_V  = OFF_BL + SZ_BL;                     // v (B,C,O)
constexpr size_t SZ_V   = (size_t)BDIM * CO;                  // 163,840
constexpr size_t OFF_ST = OFF_V + SZ_V;                       // stats (B,C,2): max, 1/sumexp
constexpr size_t SZ_ST  = (size_t)BDIM * CDIM * 2;            // 20,480
constexpr size_t OFF_SP = OFF_ST + SZ_ST;                     // s partials (RSPLIT,B,C,O) f32
constexpr size_t SZ_SP  = (size_t)RSPLIT * BDIM * CO;         // 2,621,440
constexpr size_t OFF_WF = OFF_SP + SZ_SP;                     // W fragments, f16 (2 per float)
// WF: [288 rq][10 c][64 lane][8 j] f16 = 1,474,560 f16 = 737,280 float-units
// total ws use: 14,602,240 + 737,280 = 15,339,520 floats = 61.4 MB

// ---------------------------------------------------------------------------
// k_wprep: W (R,I,C,O) f32 -> fragment-ordered f16 for the MFMA B operand.
// B-frag (16x16x32): lane l holds B[k=(l>>4)*8+j][n=l&15], k = r_loc*8 + i.
// WF[((rq*10+c)*64+l)*8 + j] = (f16) W[rq*4 + (l>>4)][i=j][c][o=l&15]
// ---------------------------------------------------------------------------
__global__ __launch_bounds__(256) void k_wprep(const float* __restrict__ W,
                                               half_t* __restrict__ WF) {
    int g = blockIdx.x * 256 + threadIdx.x;    // (rq*10+c)*64 + lane ; total 184320
    int lane = g & 63;
    int rc = g >> 6;
    int c = rc % 10;
    int rq = rc / 10;
    int r = rq * 4 + (lane >> 4);
    int o = lane & 15;
    const float* wp = W + (size_t)r * IDIM * CO + c * ODIM + o;
    f16x8 v;
#pragma unroll
    for (int j = 0; j < 8; ++j) v[j] = (half_t)wp[(size_t)j * CO];
    *(f16x8*)(WF + (size_t)g * 8) = v;
}

// ---------------------------------------------------------------------------
// k_s_mfma: s_part[split][b][c][o] = sum_{r in split} cval(b,r,c)*u_hat(b,r,c,o)
//   = sum_{ri} (cval*x)[b,ri] * W[ri,c,o]   (per-capsule GEMM, K folded over r,i)
// MODE 0: cval = 1 (scaled 1/R at write) ; MODE 1: cval = exp(bl-max)*inv_sumexp
// Block: 256 thr (4 waves), b-tile 32. Wave w: bsub = w>>1, capsules (w&1)*5..+4.
// ---------------------------------------------------------------------------
template <int MODE>
__global__ __launch_bounds__(256) void k_s_mfma(const float* __restrict__ x,
                                                const half_t* __restrict__ WF,
                                                const float* __restrict__ bl,
                                                const float* __restrict__ stats,
                                                float* __restrict__ s_part) {
    __shared__ half_t xs[CH_R * 32 * IDIM];     // [rr][bb][i] f16, 4 KB
    __shared__ float cvl[CH_R * 32 * CDIM];     // [rr][bb][cc] f32, 10 KB
    __shared__ float sts[32 * CDIM * 2];        // stats tile, 2.5 KB
    const int t = threadIdx.x;
    const int l = t & 63, w = t >> 6;
    const int b0 = blockIdx.x * 32;
    const int rg0 = blockIdx.y * R_PER_SPLIT;
    const int cbase = (w & 1) * 5;
    const int bsub = w >> 1;
    const int row = l & 15;                     // A-operand row (b within 16-tile)
    const int kg = l >> 4;                      // k-group: r within quad

    if (MODE == 1) {
        for (int e = t; e < 32 * CDIM * 2; e += 256)
            sts[e] = stats[(size_t)b0 * CDIM * 2 + e];
    }
    __syncthreads();

    f32x4 acc[5];
#pragma unroll
    for (int s = 0; s < 5; ++s) acc[s] = (f32x4){0.f, 0.f, 0.f, 0.f};

    for (int ch = 0; ch < R_PER_SPLIT / CH_R; ++ch) {
        const int r0c = rg0 + ch * CH_R;
        // stage x chunk: 8 r x 32 b x 8 i, f32 -> f16
        for (int e = t; e < 512; e += 256) {
            int rr = e >> 6, rem = e & 63, bb = rem >> 1, q = rem & 1;
            const float4 x4 = *(const float4*)(
                x + ((size_t)(b0 + bb) * RDIM + r0c + rr) * IDIM + q * 4);
            f16x4 h;
            h[0] = (half_t)x4.x; h[1] = (half_t)x4.y;
            h[2] = (half_t)x4.z; h[3] = (half_t)x4.w;
            *(f16x4*)&xs[(rr * 32 + bb) * IDIM + q * 4] = h;
        }
        if (MODE == 1) {
            // stage coefficients: 8 r x 32 b x 10 c
            for (int e = t; e < CH_R * 32 * CDIM; e += 256) {
                int bb = e / (CH_R * CDIM);
                int rem = e - bb * (CH_R * CDIM);   // rr*10+cc
                int rr = rem / CDIM, cc = rem - rr * CDIM;
                float bv = bl[(size_t)(b0 + bb) * RDIM * CDIM +
                              (size_t)(r0c + rr) * CDIM + cc];
                cvl[(rr * 32 + bb) * CDIM + cc] =
                    __expf(bv - sts[bb * 20 + cc * 2]) * sts[bb * 20 + cc * 2 + 1];
            }
        }
        __syncthreads();

#pragma unroll
        for (int rq = 0; rq < CH_R / 4; ++rq) {        // 2 k-steps of K=32 (4 r x 8 i)
            const int rr = rq * 4 + kg;
            const f16x8 xv = *(const f16x8*)&xs[(rr * 32 + bsub * 16 + row) * IDIM];
            const int rqg = (r0c >> 2) + rq;           // global r-quad
#pragma unroll
            for (int s = 0; s < 5; ++s) {
                const int cc = cbase + s;
                float cval = (MODE == 1)
                    ? cvl[(rr * 32 + bsub * 16 + row) * CDIM + cc] : 1.0f;
                half_t chf = (half_t)cval;
                f16x8 av;
#pragma unroll
                for (int j = 0; j < 8; ++j) av[j] = xv[j] * chf;
                const f16x8 bv = *(const f16x8*)(
                    WF + ((size_t)(rqg * CDIM + cc) * 64 + l) * 8);
                acc[s] = __builtin_amdgcn_mfma_f32_16x16x32_f16(av, bv, acc[s], 0, 0, 0);
            }
        }
        __syncthreads();
    }

    // D layout: col(o) = l&15, row(b_local) = kg*4 + reg  [m89-verified]
#pragma unroll
    for (int s = 0; s < 5; ++s) {
        const int cc = cbase + s;
#pragma unroll
        for (int reg = 0; reg < 4; ++reg) {
            float val = acc[s][reg];
            if (MODE == 0) val *= (1.0f / RDIM);
            int brow = b0 + bsub * 16 + kg * 4 + reg;
            s_part[((size_t)blockIdx.y * BDIM + brow) * CO + cc * ODIM + (l & 15)] = val;
        }
    }
}

// ---------------------------------------------------------------------------
// k_squash: s = sum over partials; v = (n/(n+1)) * s / sqrt(n), n = |s|^2 over O
// ---------------------------------------------------------------------------
__global__ __launch_bounds__(256) void k_squash(const float* __restrict__ s_part,
                                                float* __restrict__ dst) {
    int g = blockIdx.x * 256 + threadIdx.x;   // grid covers B*CO = 163840
    int b = g / CO;
    int co = g - b * CO;
    float s = 0.f;
#pragma unroll
    for (int p = 0; p < RSPLIT; ++p)
        s += s_part[((size_t)p * BDIM + b) * CO + co];
    float sq = s * s;
    sq += __shfl_xor(sq, 1, 16);
    sq += __shfl_xor(sq, 2, 16);
    sq += __shfl_xor(sq, 4, 16);
    sq += __shfl_xor(sq, 8, 16);
    float n = sq;
    float val = (n / (n + 1.0f)) * s / sqrtf(n);
    dst[g] = val;
}

// ---------------------------------------------------------------------------
// k_b: bl[b,r,c] (+)= sum_o u_hat(b,r,c,o) * v[b,c,o]
// block: 16 r x 64 batches, 640 threads = (bt, c)
// W slice staged as [i][c][20] (o padded 16->20) -> c-stride 80 B kills the
// 5-way bank-group conflict seen at 3.33e7 SQ_LDS_BANK_CONFLICT/dispatch.
// ---------------------------------------------------------------------------
template <int ACC>
__global__ __launch_bounds__(640) void k_b(const float* __restrict__ x,
                                           const float* __restrict__ W,
                                           const float* __restrict__ v,
                                           float* __restrict__ bl) {
    constexpr int RT = 16, BT = 64;
    __shared__ float xs[RT][BT][IDIM + 1];   // pad to 9 -> conflict-free (36,864 B)
    __shared__ float wsm2[IDIM][CDIM][20];   // o padded to 20 (6,400 B)
    const int t = threadIdx.x;
    const int r0 = blockIdx.x * RT;
    const int b0 = blockIdx.y * BT;
    const int bt = t / CDIM;                 // 0..63
    const int c = t - bt * CDIM;             // 0..9

    // stage x tile: 16 r x 64 b x 8 i
    for (int e = t; e < RT * BT * IDIM; e += 640) {
        int rr = e >> 9;
        int rem = e & 511;
        int bb = rem >> 3;
        int i = rem & 7;
        xs[rr][bb][i] = x[(size_t)(b0 + bb) * RDIM * IDIM + (size_t)(r0 + rr) * IDIM + i];
    }

    // v row for this (batch, capsule) in registers
    float vr[ODIM];
    {
        const float* vp = v + (size_t)(b0 + bt) * CO + c * ODIM;
#pragma unroll
        for (int o = 0; o < ODIM; o += 4) {
            float4 q = *reinterpret_cast<const float4*>(vp + o);
            vr[o] = q.x; vr[o + 1] = q.y; vr[o + 2] = q.z; vr[o + 3] = q.w;
        }
    }

    for (int rr = 0; rr < RT; ++rr) {
        __syncthreads();   // protect wsm2 from previous iteration's readers (and xs on iter 0)
        for (int e = t; e < IDIM * CO; e += 640) {
            int i = e / CO;
            int rem = e - i * CO;            // c*16 + o
            wsm2[i][rem >> 4][rem & 15] = W[(size_t)(r0 + rr) * IDIM * CO + e];
        }
        __syncthreads();

        float u[ODIM];
#pragma unroll
        for (int o = 0; o < ODIM; ++o) u[o] = 0.f;
#pragma unroll
        for (int i = 0; i < IDIM; ++i) {
            float xi = xs[rr][bt][i];
#pragma unroll
            for (int o4 = 0; o4 < ODIM; o4 += 4) {
                float4 w4 = *reinterpret_cast<const float4*>(&wsm2[i][c][o4]);
                u[o4]     += xi * w4.x;
                u[o4 + 1] += xi * w4.y;
                u[o4 + 2] += xi * w4.z;
                u[o4 + 3] += xi * w4.w;
            }
        }
        float bacc = 0.f;
#pragma unroll
        for (int o = 0; o < ODIM; ++o) bacc += u[o] * vr[o];

        size_t idx = (size_t)(b0 + bt) * RDIM * CDIM + (size_t)(r0 + rr) * CDIM + c;
        if (ACC) {
            bl[idx] = bl[idx] + bacc;
        } else {
            bl[idx] = bacc;
        }
    }
}

// ---------------------------------------------------------------------------
// k_stats: per (b,c): max over r of bl, and 1/sum(exp(bl-max))
// ---------------------------------------------------------------------------
__global__ __launch_bounds__(256) void k_stats(const float* __restrict__ bl,
                                               float* __restrict__ stats) {
    __shared__ float sb[RDIM * CDIM];   // 46,080 B
    __shared__ float red[4];
    const int t = threadIdx.x;
    const int b = blockIdx.x;
    const int wave = t >> 6, lane = t & 63;

    for (int e = t; e < RDIM * CDIM; e += 256)
        sb[e] = bl[(size_t)b * RDIM * CDIM + e];
    __syncthreads();

    for (int c = 0; c < CDIM; ++c) {
        float m = -1e30f;
        for (int r = t; r < RDIM; r += 256)
            m = fmaxf(m, sb[r * CDIM + c]);
        for (int d = 1; d < 64; d <<= 1)
            m = fmaxf(m, __shfl_xor(m, d, 64));
        if (lane == 0) red[wave] = m;
        __syncthreads();
        m = fmaxf(fmaxf(red[0], red[1]), fmaxf(red[2], red[3]));
        __syncthreads();

        float se = 0.f;
        for (int r = t; r < RDIM; r += 256)
            se += __expf(sb[r * CDIM + c] - m);
        for (int d = 1; d < 64; d <<= 1)
            se += __shfl_xor(se, d, 64);
        if (lane == 0) red[wave] = se;
        __syncthreads();
        se = red[0] + red[1] + red[2] + red[3];
        if (t == 0) {
            stats[(size_t)b * CDIM * 2 + c * 2 + 0] = m;
            stats[(size_t)b * CDIM * 2 + c * 2 + 1] = 1.0f / se;
        }
        __syncthreads();
    }
}

// ---------------------------------------------------------------------------
extern "C" void kernel_launch(void* const* d_in, const int* in_sizes, int n_in,
                              void* d_out, int out_size, void* d_ws, size_t ws_size,
                              hipStream_t stream) {
    const float* x = (const float*)d_in[0];
    const float* W = (const float*)d_in[1];
    float* out = (float*)d_out;
    float* ws = (float*)d_ws;

    float* bl = ws + OFF_BL;
    float* v  = ws + OFF_V;
    float* st = ws + OFF_ST;
    float* sp = ws + OFF_SP;
    half_t* wf = (half_t*)(ws + OFF_WF);

    dim3 gs(BDIM / 32, RSPLIT);                // 32 x 16 = 512 blocks of 256
    dim3 gb(RDIM / 16, BDIM / 64);             // 72 x 16 blocks of 640

    // one-time (per launch) W fragment prep: 184,320 threads
    k_wprep<<<720, 256, 0, stream>>>(W, wf);

    // iteration 0: softmax(0) is uniform -> s0 = mean_r u_hat
    k_s_mfma<0><<<gs, 256, 0, stream>>>(x, wf, bl, st, sp);
    k_squash<<<(BDIM * CO) / 256, 256, 0, stream>>>(sp, v);
    k_b<0><<<gb, 640, 0, stream>>>(x, W, v, bl);     // b1 = u_hat . v0

    // iteration 1
    k_stats<<<BDIM, 256, 0, stream>>>(bl, st);
    k_s_mfma<1><<<gs, 256, 0, stream>>>(x, wf, bl, st, sp);
    k_squash<<<(BDIM * CO) / 256, 256, 0, stream>>>(sp, v);
    k_b<1><<<gb, 640, 0, stream>>>(x, W, v, bl);     // b2 = b1 + u_hat . v1

    // iteration 2 (final; no b update)
    k_stats<<<BDIM, 256, 0, stream>>>(bl, st);
    k_s_mfma<1><<<gs, 256, 0, stream>>>(x, wf, bl, st, sp);
    k_squash<<<(BDIM * CO) / 256, 256, 0, stream>>>(sp, out);
}